// Round 1
// baseline (215.484 us; speedup 1.0000x reference)
//
#include <hip/hip_runtime.h>
#include <cmath>

// ---------------- constants (match reference) ----------------
static constexpr int Tn = 1024, Dn = 512, Hn = 8, Cn = 64, DQn = 256,
                     NIn = 2, CIn = 64, TK = 32, LM = 16, NW = 128, Pn = 128;
#define NEGV (-1e30f)

// ---------------- segmented fp32 GEMM ----------------
// C_seg = A @ B_seg for up to 6 column-segments sharing the same A.
// Tile 64x64, K-step 16, 256 threads, 4x4 per thread.
struct SegParams {
  const float* B[6];
  float* C[6];
  int width[6];   // each a multiple of 64
  int tstart[6];  // starting col-tile index of segment
  int nseg;
};

__global__ __launch_bounds__(256) void sgemm_seg(const float* __restrict__ A,
                                                 int K, SegParams sp) {
  const int ct = blockIdx.x, rt = blockIdx.y;
  int s = 0;
  while (s + 1 < sp.nseg && ct >= sp.tstart[s + 1]) ++s;
  const float* __restrict__ Bm = sp.B[s];
  float* __restrict__ Cm = sp.C[s];
  const int ldb = sp.width[s];
  const int col0 = (ct - sp.tstart[s]) * 64;
  const int row0 = rt * 64;

  __shared__ float As[16][64];
  __shared__ float Bs[16][64];

  const int tid = threadIdx.x;
  const int tx = tid & 15, ty = tid >> 4;
  const int am = tid & 63, ak4 = (tid >> 6) << 2;   // A: row am, k-offset ak4..+3
  const int bn4 = (tid & 15) << 2, bk = tid >> 4;   // B: k bk, col bn4..+3

  float acc[4][4] = {};

  for (int k0 = 0; k0 < K; k0 += 16) {
    float4 av = *reinterpret_cast<const float4*>(&A[(row0 + am) * K + k0 + ak4]);
    As[ak4 + 0][am] = av.x;
    As[ak4 + 1][am] = av.y;
    As[ak4 + 2][am] = av.z;
    As[ak4 + 3][am] = av.w;
    *reinterpret_cast<float4*>(&Bs[bk][bn4]) =
        *reinterpret_cast<const float4*>(&Bm[(k0 + bk) * ldb + col0 + bn4]);
    __syncthreads();
#pragma unroll
    for (int k = 0; k < 16; ++k) {
      float4 a4 = *reinterpret_cast<const float4*>(&As[k][ty << 2]);
      float4 b4 = *reinterpret_cast<const float4*>(&Bs[k][tx << 2]);
      float a[4] = {a4.x, a4.y, a4.z, a4.w};
      float b[4] = {b4.x, b4.y, b4.z, b4.w};
#pragma unroll
      for (int i = 0; i < 4; ++i)
#pragma unroll
        for (int j = 0; j < 4; ++j) acc[i][j] += a[i] * b[j];
    }
    __syncthreads();
  }
#pragma unroll
  for (int i = 0; i < 4; ++i) {
    float4 v = make_float4(acc[i][0], acc[i][1], acc[i][2], acc[i][3]);
    *reinterpret_cast<float4*>(&Cm[(row0 + (ty << 2) + i) * ldb + col0 + (tx << 2)]) = v;
  }
}

// ---------------- phrase aggregation ----------------
// One block per phrase. tid = h*64+c. Computes c_csa, k_csa (rms+rope@pos),
// k_idx (softmax-agg + rope@pos, no rms).
__global__ __launch_bounds__(512) void phrase_kernel(
    const int* __restrict__ maskbuf, const int* __restrict__ tokbuf,
    const int* __restrict__ endbuf, const float* __restrict__ hckv,
    const float* __restrict__ hcz, const float* __restrict__ hikv,
    const float* __restrict__ hiz, const float* __restrict__ Bcsa,
    const float* __restrict__ Bidx, const float* __restrict__ knw,
    float* __restrict__ ccsa, float* __restrict__ kcsa,
    float* __restrict__ kidx) {
  const int p = blockIdx.x;
  const int tid = threadIdx.x;
  __shared__ int s_bytemode;
  __shared__ int s_tok[LM];
  __shared__ int s_m[LM];
  __shared__ int s_pos, s_anyv;

  // Detect whether the bool mask was staged as int32 (one per elem) or bytes.
  // (P*LM = 2048 elems -> 512 words if bytes, 2048 words if int32; first 512
  //  words are safe to read either way. Any word value >1 => byte packing.)
  if (tid == 0) s_bytemode = 0;
  __syncthreads();
  {
    unsigned w = ((const unsigned*)maskbuf)[tid];  // tid in [0,512)
    if (w > 1u) atomicOr(&s_bytemode, 1);
  }
  __syncthreads();
  const int bytemode = s_bytemode;
  if (tid < LM) {
    int mv;
    if (bytemode)
      mv = ((const unsigned char*)maskbuf)[p * LM + tid] != 0;
    else
      mv = maskbuf[p * LM + tid] != 0;
    s_m[tid] = mv;
    s_tok[tid] = tokbuf[p * LM + tid];
  }
  if (tid == 0) {
    int e = endbuf[p];
    s_pos = min(max(e, 0), Tn - 1);
  }
  __syncthreads();
  if (tid == 0) {
    int any = 0;
    for (int l = 0; l < LM; ++l) any |= s_m[l];
    s_anyv = any;
  }
  __syncthreads();
  const int anyv = s_anyv;
  const int pos = s_pos;
  const int c = tid & 63;
  const float fr = (float)pos * powf(10000.0f, -(float)(c & 31) / 32.0f);
  const float cv = cosf(fr), sv = sinf(fr);
  const float sgn = (c < 32) ? -1.f : 1.f;

  // ----- c_csa over channel hc = tid
  {
    float z[LM];
    float zmax = NEGV;
#pragma unroll
    for (int l = 0; l < LM; ++l) {
      float zv = hcz[s_tok[l] * Dn + tid] + Bcsa[l * (Hn * Cn) + tid];
      zv = s_m[l] ? zv : NEGV;
      z[l] = zv;
      zmax = fmaxf(zmax, zv);
    }
    float den = 0.f, num = 0.f;
#pragma unroll
    for (int l = 0; l < LM; ++l) {
      float e = expf(z[l] - zmax);
      den += e;
      num += e * hckv[s_tok[l] * Dn + tid];
    }
    float cc = anyv ? (num / den) : 0.f;
    ccsa[p * (Hn * Cn) + tid] = cc;

    // rms over the 64 channels of this head (one wave == one head)
    float ss = cc * cc;
#pragma unroll
    for (int off = 32; off; off >>= 1) ss += __shfl_xor(ss, off, 64);
    float kn = cc * rsqrtf(ss / (float)Cn + 1e-6f) * knw[c];
    float pr = __shfl_xor(kn, 32, 64);
    kcsa[p * (Hn * Cn) + tid] = kn * cv + sgn * pr * sv;
  }

  // ----- k_idx (first wave only, ci = tid)
  if (tid < CIn) {
    float zk[LM];
    float zm = NEGV;
#pragma unroll
    for (int l = 0; l < LM; ++l) {
      float zv = hiz[s_tok[l] * CIn + tid] + Bidx[l * CIn + tid];
      zv = s_m[l] ? zv : NEGV;
      zk[l] = zv;
      zm = fmaxf(zm, zv);
    }
    float dk = 0.f, nk = 0.f;
#pragma unroll
    for (int l = 0; l < LM; ++l) {
      float e = expf(zk[l] - zm);
      dk += e;
      nk += e * hikv[s_tok[l] * CIn + tid];
    }
    float ki = anyv ? (nk / dk) : 0.f;
    float pr = __shfl_xor(ki, 32, 64);
    kidx[p * CIn + tid] = ki * cv + sgn * pr * sv;  // rope, no rms
  }
}

// ---------------- RMS+RoPE for q (in place) and k_sw ----------------
__global__ __launch_bounds__(512) void rmsrope_kernel(
    float* __restrict__ q, const float* __restrict__ kv,
    float* __restrict__ ksw, const float* __restrict__ qnw,
    const float* __restrict__ knw) {
  const int t = blockIdx.x;
  const int tid = threadIdx.x;
  const int c = tid & 63;
  const float fr = (float)t * powf(10000.0f, -(float)(c & 31) / 32.0f);
  const float cv = cosf(fr), sv = sinf(fr);
  const float sgn = (c < 32) ? -1.f : 1.f;
  {
    float x = q[t * Dn + tid];
    float ss = x * x;
#pragma unroll
    for (int off = 32; off; off >>= 1) ss += __shfl_xor(ss, off, 64);
    float xr = x * rsqrtf(ss / (float)Cn + 1e-6f) * qnw[c];
    float pr = __shfl_xor(xr, 32, 64);
    q[t * Dn + tid] = xr * cv + sgn * pr * sv;
  }
  {
    float y = kv[t * Dn + tid];
    float ss = y * y;
#pragma unroll
    for (int off = 32; off; off >>= 1) ss += __shfl_xor(ss, off, 64);
    float yr = y * rsqrtf(ss / (float)Cn + 1e-6f) * knw[c];
    float pr = __shfl_xor(yr, 32, 64);
    ksw[t * Dn + tid] = yr * cv + sgn * pr * sv;
  }
}

// ---------------- phrase scores + top-32 ----------------
__global__ __launch_bounds__(128) void score_topk_kernel(
    const float* __restrict__ hbuf, const float* __restrict__ Ww,
    const float* __restrict__ qi, const float* __restrict__ kidx,
    const int* __restrict__ endbuf, int* __restrict__ sel,
    int* __restrict__ selok) {
  const int t = blockIdx.x;
  const int tid = threadIdx.x;
  __shared__ float sqi[NIn * CIn];
  __shared__ float sI[Pn];
  __shared__ float sp0[128], sp1[128];

  sqi[tid] = qi[t * (NIn * CIn) + tid];
  float p0 = 0.f, p1 = 0.f;
#pragma unroll
  for (int e4 = 0; e4 < 4; ++e4) {
    int e = tid * 4 + e4;
    float hv = hbuf[t * Dn + e];
    p0 += hv * Ww[e * NIn + 0];
    p1 += hv * Ww[e * NIn + 1];
  }
  sp0[tid] = p0;
  sp1[tid] = p1;
  __syncthreads();
  for (int srd = 64; srd; srd >>= 1) {
    if (tid < srd) {
      sp0[tid] += sp0[tid + srd];
      sp1[tid] += sp1[tid + srd];
    }
    __syncthreads();
  }
  const float ww0 = sp0[0], ww1 = sp1[0];

  {
    const int p = tid;
    const float* kp = &kidx[p * CIn];
    float s0 = 0.f, s1 = 0.f;
#pragma unroll 16
    for (int ci = 0; ci < CIn; ++ci) {
      float kc = kp[ci];
      s0 += sqi[ci] * kc;
      s1 += sqi[CIn + ci] * kc;
    }
    float Iv = fmaxf(s0, 0.f) * ww0 + fmaxf(s1, 0.f) * ww1;
    int e = endbuf[p];
    if (!(e <= t && e >= 0)) Iv = NEGV;
    sI[p] = Iv;
  }
  __syncthreads();

  // top-32 with JAX tie-break (lower index wins), one wave
  if (tid < 64) {
    float v0 = sI[tid], v1 = sI[tid + 64];
    for (int it = 0; it < TK; ++it) {
      float bv;
      int bi;
      if (v0 >= v1) { bv = v0; bi = tid; } else { bv = v1; bi = tid + 64; }
#pragma unroll
      for (int off = 32; off; off >>= 1) {
        float ov = __shfl_xor(bv, off, 64);
        int oi = __shfl_xor(bi, off, 64);
        if (ov > bv || (ov == bv && oi < bi)) { bv = ov; bi = oi; }
      }
      if (tid == 0) {
        sel[t * TK + it] = bi;
        selok[t * TK + it] = (bv > NEGV * 0.5f) ? 1 : 0;
      }
      if (bi == tid) v0 = -3.4e38f;
      if (bi == tid + 64) v1 = -3.4e38f;
    }
  }
}

// ---------------- attention ----------------
// Block per t, wave per head. Logits: lane j handles idx j, j+64, and
// (j<32: idx 128+j, j==32: sink). idx<32 => csa, 32..159 => window w=idx-32.
__global__ __launch_bounds__(512) void attn_kernel(
    const float* __restrict__ q, const float* __restrict__ ksw,
    const float* __restrict__ kv, const float* __restrict__ kcsa,
    const float* __restrict__ ccsa, const int* __restrict__ sel,
    const int* __restrict__ selok, const float* __restrict__ sink,
    float* __restrict__ attno) {
  const int t = blockIdx.x;
  const int tid = threadIdx.x;
  const int h = tid >> 6, lane = tid & 63;
  __shared__ float sq[Hn][Cn];
  __shared__ int s_sel[TK], s_ok[TK];
  __shared__ float plog[Hn][164];

  sq[h][lane] = q[t * Dn + tid];
  if (tid < TK) {
    s_sel[tid] = sel[t * TK + tid];
    s_ok[tid] = selok[t * TK + tid];
  }
  __syncthreads();

  float l0 = NEGV, l1 = NEGV, l2 = NEGV;
  const float* qh = sq[h];
  // L0: idx = lane
  if (lane < TK) {
    if (s_ok[lane]) {
      const float* kp = &kcsa[s_sel[lane] * Dn + h * Cn];
      float acc = 0.f;
#pragma unroll 16
      for (int c2 = 0; c2 < Cn; ++c2) acc += qh[c2] * kp[c2];
      l0 = acc * 0.125f;
    }
  } else {
    int src = t + (lane - TK) - (NW - 1);
    if (src >= 0) {
      const float* kp = &ksw[src * Dn + h * Cn];
      float acc = 0.f;
#pragma unroll 16
      for (int c2 = 0; c2 < Cn; ++c2) acc += qh[c2] * kp[c2];
      l0 = acc * 0.125f;
    }
  }
  // L1: idx = lane+64 -> w = lane+32
  {
    int src = t + (lane + 32) - (NW - 1);
    if (src >= 0) {
      const float* kp = &ksw[src * Dn + h * Cn];
      float acc = 0.f;
#pragma unroll 16
      for (int c2 = 0; c2 < Cn; ++c2) acc += qh[c2] * kp[c2];
      l1 = acc * 0.125f;
    }
  }
  // L2: lane<32 -> w = lane+96 ; lane==32 -> sink
  if (lane < 32) {
    int src = t + (lane + 96) - (NW - 1);
    if (src >= 0) {
      const float* kp = &ksw[src * Dn + h * Cn];
      float acc = 0.f;
#pragma unroll 16
      for (int c2 = 0; c2 < Cn; ++c2) acc += qh[c2] * kp[c2];
      l2 = acc * 0.125f;
    }
  } else if (lane == 32) {
    l2 = sink[h];
  }

  float m = fmaxf(l0, fmaxf(l1, l2));
#pragma unroll
  for (int off = 32; off; off >>= 1) m = fmaxf(m, __shfl_xor(m, off, 64));
  float e0 = expf(l0 - m), e1 = expf(l1 - m), e2 = expf(l2 - m);
  float sden = e0 + e1 + e2;
#pragma unroll
  for (int off = 32; off; off >>= 1) sden += __shfl_xor(sden, off, 64);
  const float inv = 1.f / sden;
  plog[h][lane] = e0 * inv;
  plog[h][lane + 64] = e1 * inv;
  if (lane < 33) plog[h][lane + 128] = e2 * inv;  // 160 = sink (unused below)
  __syncthreads();

  float out = 0.f;
  const int cbase = h * Cn + lane;
  for (int idx = 0; idx < TK; ++idx) {
    float pv = plog[h][idx];
    if (pv != 0.f) out += pv * ccsa[s_sel[idx] * Dn + cbase];
  }
  for (int w = 0; w < NW; ++w) {
    float pv = plog[h][TK + w];
    if (pv != 0.f) {
      int src = t + w - (NW - 1);
      out += pv * kv[src * Dn + cbase];
    }
  }
  attno[t * Dn + tid] = out;
}

// ---------------- host launcher ----------------
extern "C" void kernel_launch(void* const* d_in, const int* in_sizes, int n_in,
                              void* d_out, int out_size, void* d_ws,
                              size_t ws_size, hipStream_t stream) {
  const float* h = (const float*)d_in[0];
  const int* mask = (const int*)d_in[1];
  const int* tok = (const int*)d_in[2];
  const int* endp = (const int*)d_in[3];
  const float* W_dq = (const float*)d_in[5];
  const float* W_uq = (const float*)d_in[6];
  const float* W_csa_kv = (const float*)d_in[7];
  const float* W_csa_z = (const float*)d_in[8];
  const float* B_csa = (const float*)d_in[9];
  const float* W_idx_kv = (const float*)d_in[10];
  const float* W_idx_z = (const float*)d_in[11];
  const float* B_idx = (const float*)d_in[12];
  const float* W_iuq = (const float*)d_in[13];
  const float* W_w = (const float*)d_in[14];
  const float* W_swkv = (const float*)d_in[15];
  const float* qnw = (const float*)d_in[16];
  const float* knw = (const float*)d_in[17];
  const float* W_o = (const float*)d_in[18];
  const float* sink = (const float*)d_in[19];

  float* ws = (float*)d_ws;
  float* q_lat = ws + 0;        // 1024*256
  float* hckv = ws + 262144;    // 1024*512
  float* hcz = ws + 786432;     // 1024*512 (reused as attn-out)
  float* hikv = ws + 1310720;   // 1024*64
  float* hiz = ws + 1376256;    // 1024*64
  float* kvb = ws + 1441792;    // 1024*512
  float* qbuf = ws + 1966080;   // 1024*512 (qraw -> q in place)
  float* qib = ws + 2490368;    // 1024*128
  float* kswb = ws + 2621440;   // 1024*512
  float* ccsa = ws + 3145728;   // 128*512
  float* kcsa = ws + 3211264;   // 128*512
  float* kidx = ws + 3276800;   // 128*64
  int* seli = (int*)(ws + 3284992);   // 1024*32
  int* selok = (int*)(ws + 3317760);  // 1024*32
  float* attno = hcz;                 // alias: hcz dead after phrase_kernel
  float* outp = (float*)d_out;

  // K1: h @ {W_dq, W_csa_kv, W_csa_z, W_idx_kv, W_idx_z, W_swkv}
  {
    SegParams sp;
    const float* b[6] = {W_dq, W_csa_kv, W_csa_z, W_idx_kv, W_idx_z, W_swkv};
    float* c[6] = {q_lat, hckv, hcz, hikv, hiz, kvb};
    int w[6] = {256, 512, 512, 64, 64, 512};
    int ts = 0;
    sp.nseg = 6;
    for (int i = 0; i < 6; ++i) {
      sp.B[i] = b[i]; sp.C[i] = c[i]; sp.width[i] = w[i]; sp.tstart[i] = ts;
      ts += w[i] / 64;
    }
    sgemm_seg<<<dim3(30, 16), 256, 0, stream>>>(h, 512, sp);
  }
  // K2: q_lat @ {W_uq, W_iuq}
  {
    SegParams sp;
    sp.nseg = 2;
    sp.B[0] = W_uq;  sp.C[0] = qbuf; sp.width[0] = 512; sp.tstart[0] = 0;
    sp.B[1] = W_iuq; sp.C[1] = qib;  sp.width[1] = 128; sp.tstart[1] = 8;
    sgemm_seg<<<dim3(10, 16), 256, 0, stream>>>(q_lat, 256, sp);
  }
  // K3: phrase aggregation
  phrase_kernel<<<Pn, 512, 0, stream>>>(mask, tok, endp, hckv, hcz, hikv, hiz,
                                        B_csa, B_idx, knw, ccsa, kcsa, kidx);
  // K5: q (in place) and k_sw
  rmsrope_kernel<<<Tn, 512, 0, stream>>>(qbuf, kvb, kswb, qnw, knw);
  // K4: scores + top-32
  score_topk_kernel<<<Tn, 128, 0, stream>>>(h, W_w, qib, kidx, endp, seli,
                                            selok);
  // K6: attention (writes attno, aliases hcz)
  attn_kernel<<<Tn, 512, 0, stream>>>(qbuf, kswb, kvb, kcsa, ccsa, seli, selok,
                                      sink, attno);
  // K7: attno @ W_o -> out
  {
    SegParams sp;
    sp.nseg = 1;
    sp.B[0] = W_o; sp.C[0] = outp; sp.width[0] = 512; sp.tstart[0] = 0;
    sgemm_seg<<<dim3(8, 16), 256, 0, stream>>>(attno, 512, sp);
  }
  (void)in_sizes; (void)n_in; (void)out_size; (void)ws_size;
}

// Round 2
// 181.767 us; speedup vs baseline: 1.1855x; 1.1855x over previous
//
#include <hip/hip_runtime.h>
#include <cmath>

// ---------------- constants (match reference) ----------------
static constexpr int Tn = 1024, Dn = 512, Hn = 8, Cn = 64, DQn = 256,
                     NIn = 2, CIn = 64, TK = 32, LM = 16, NW = 128, Pn = 128;
#define NEGV (-1e30f)

// ---------------- segmented fp32 GEMM ----------------
struct SegParams {
  const float* B[6];
  float* C[6];
  int width[6];   // each a multiple of 64
  int tstart[6];  // starting col-tile index of segment
  int nseg;
};

__global__ __launch_bounds__(256) void sgemm_seg(const float* __restrict__ A,
                                                 int K, SegParams sp) {
  const int ct = blockIdx.x, rt = blockIdx.y;
  int s = 0;
  while (s + 1 < sp.nseg && ct >= sp.tstart[s + 1]) ++s;
  const float* __restrict__ Bm = sp.B[s];
  float* __restrict__ Cm = sp.C[s];
  const int ldb = sp.width[s];
  const int col0 = (ct - sp.tstart[s]) * 64;
  const int row0 = rt * 64;

  __shared__ float As[16][64];
  __shared__ float Bs[16][64];

  const int tid = threadIdx.x;
  const int tx = tid & 15, ty = tid >> 4;
  const int am = tid & 63, ak4 = (tid >> 6) << 2;
  const int bn4 = (tid & 15) << 2, bk = tid >> 4;

  float acc[4][4] = {};

  for (int k0 = 0; k0 < K; k0 += 16) {
    float4 av = *reinterpret_cast<const float4*>(&A[(row0 + am) * K + k0 + ak4]);
    As[ak4 + 0][am] = av.x;
    As[ak4 + 1][am] = av.y;
    As[ak4 + 2][am] = av.z;
    As[ak4 + 3][am] = av.w;
    *reinterpret_cast<float4*>(&Bs[bk][bn4]) =
        *reinterpret_cast<const float4*>(&Bm[(k0 + bk) * ldb + col0 + bn4]);
    __syncthreads();
#pragma unroll
    for (int k = 0; k < 16; ++k) {
      float4 a4 = *reinterpret_cast<const float4*>(&As[k][ty << 2]);
      float4 b4 = *reinterpret_cast<const float4*>(&Bs[k][tx << 2]);
      float a[4] = {a4.x, a4.y, a4.z, a4.w};
      float b[4] = {b4.x, b4.y, b4.z, b4.w};
#pragma unroll
      for (int i = 0; i < 4; ++i)
#pragma unroll
        for (int j = 0; j < 4; ++j) acc[i][j] += a[i] * b[j];
    }
    __syncthreads();
  }
#pragma unroll
  for (int i = 0; i < 4; ++i) {
    float4 v = make_float4(acc[i][0], acc[i][1], acc[i][2], acc[i][3]);
    *reinterpret_cast<float4*>(&Cm[(row0 + (ty << 2) + i) * ldb + col0 + (tx << 2)]) = v;
  }
}

// ---------------- phrase aggregation ----------------
__global__ __launch_bounds__(512) void phrase_kernel(
    const int* __restrict__ maskbuf, const int* __restrict__ tokbuf,
    const int* __restrict__ endbuf, const float* __restrict__ hckv,
    const float* __restrict__ hcz, const float* __restrict__ hikv,
    const float* __restrict__ hiz, const float* __restrict__ Bcsa,
    const float* __restrict__ Bidx, const float* __restrict__ knw,
    float* __restrict__ ccsa, float* __restrict__ kcsa,
    float* __restrict__ kidx) {
  const int p = blockIdx.x;
  const int tid = threadIdx.x;
  __shared__ int s_bytemode;
  __shared__ int s_tok[LM];
  __shared__ int s_m[LM];
  __shared__ int s_pos, s_anyv;

  if (tid == 0) s_bytemode = 0;
  __syncthreads();
  {
    unsigned w = ((const unsigned*)maskbuf)[tid];  // tid in [0,512)
    if (w > 1u) atomicOr(&s_bytemode, 1);
  }
  __syncthreads();
  const int bytemode = s_bytemode;
  if (tid < LM) {
    int mv;
    if (bytemode)
      mv = ((const unsigned char*)maskbuf)[p * LM + tid] != 0;
    else
      mv = maskbuf[p * LM + tid] != 0;
    s_m[tid] = mv;
    s_tok[tid] = tokbuf[p * LM + tid];
  }
  if (tid == 0) {
    int e = endbuf[p];
    s_pos = min(max(e, 0), Tn - 1);
  }
  __syncthreads();
  if (tid == 0) {
    int any = 0;
    for (int l = 0; l < LM; ++l) any |= s_m[l];
    s_anyv = any;
  }
  __syncthreads();
  const int anyv = s_anyv;
  const int pos = s_pos;
  const int c = tid & 63;
  const float fr = (float)pos * powf(10000.0f, -(float)(c & 31) / 32.0f);
  const float cv = cosf(fr), sv = sinf(fr);
  const float sgn = (c < 32) ? -1.f : 1.f;

  {
    float z[LM];
    float zmax = NEGV;
#pragma unroll
    for (int l = 0; l < LM; ++l) {
      float zv = hcz[s_tok[l] * Dn + tid] + Bcsa[l * (Hn * Cn) + tid];
      zv = s_m[l] ? zv : NEGV;
      z[l] = zv;
      zmax = fmaxf(zmax, zv);
    }
    float den = 0.f, num = 0.f;
#pragma unroll
    for (int l = 0; l < LM; ++l) {
      float e = expf(z[l] - zmax);
      den += e;
      num += e * hckv[s_tok[l] * Dn + tid];
    }
    float cc = anyv ? (num / den) : 0.f;
    ccsa[p * (Hn * Cn) + tid] = cc;

    float ss = cc * cc;
#pragma unroll
    for (int off = 32; off; off >>= 1) ss += __shfl_xor(ss, off, 64);
    float kn = cc * rsqrtf(ss / (float)Cn + 1e-6f) * knw[c];
    float pr = __shfl_xor(kn, 32, 64);
    kcsa[p * (Hn * Cn) + tid] = kn * cv + sgn * pr * sv;
  }

  if (tid < CIn) {
    float zk[LM];
    float zm = NEGV;
#pragma unroll
    for (int l = 0; l < LM; ++l) {
      float zv = hiz[s_tok[l] * CIn + tid] + Bidx[l * CIn + tid];
      zv = s_m[l] ? zv : NEGV;
      zk[l] = zv;
      zm = fmaxf(zm, zv);
    }
    float dk = 0.f, nk = 0.f;
#pragma unroll
    for (int l = 0; l < LM; ++l) {
      float e = expf(zk[l] - zm);
      dk += e;
      nk += e * hikv[s_tok[l] * CIn + tid];
    }
    float ki = anyv ? (nk / dk) : 0.f;
    float pr = __shfl_xor(ki, 32, 64);
    kidx[p * CIn + tid] = ki * cv + sgn * pr * sv;
  }
}

// ---------------- RMS+RoPE for q (in place) and k_sw ----------------
__global__ __launch_bounds__(512) void rmsrope_kernel(
    float* __restrict__ q, const float* __restrict__ kv,
    float* __restrict__ ksw, const float* __restrict__ qnw,
    const float* __restrict__ knw) {
  const int t = blockIdx.x;
  const int tid = threadIdx.x;
  const int c = tid & 63;
  const float fr = (float)t * powf(10000.0f, -(float)(c & 31) / 32.0f);
  const float cv = cosf(fr), sv = sinf(fr);
  const float sgn = (c < 32) ? -1.f : 1.f;
  {
    float x = q[t * Dn + tid];
    float ss = x * x;
#pragma unroll
    for (int off = 32; off; off >>= 1) ss += __shfl_xor(ss, off, 64);
    float xr = x * rsqrtf(ss / (float)Cn + 1e-6f) * qnw[c];
    float pr = __shfl_xor(xr, 32, 64);
    q[t * Dn + tid] = xr * cv + sgn * pr * sv;
  }
  {
    float y = kv[t * Dn + tid];
    float ss = y * y;
#pragma unroll
    for (int off = 32; off; off >>= 1) ss += __shfl_xor(ss, off, 64);
    float yr = y * rsqrtf(ss / (float)Cn + 1e-6f) * knw[c];
    float pr = __shfl_xor(yr, 32, 64);
    ksw[t * Dn + tid] = yr * cv + sgn * pr * sv;
  }
}

// ---------------- phrase scores + top-32 ----------------
__global__ __launch_bounds__(128) void score_topk_kernel(
    const float* __restrict__ hbuf, const float* __restrict__ Ww,
    const float* __restrict__ qi, const float* __restrict__ kidx,
    const int* __restrict__ endbuf, int* __restrict__ sel,
    int* __restrict__ selok) {
  const int t = blockIdx.x;
  const int tid = threadIdx.x;
  __shared__ float sqi[NIn * CIn];
  __shared__ float sI[Pn];
  __shared__ float sp0[128], sp1[128];

  sqi[tid] = qi[t * (NIn * CIn) + tid];
  float p0 = 0.f, p1 = 0.f;
#pragma unroll
  for (int e4 = 0; e4 < 4; ++e4) {
    int e = tid * 4 + e4;
    float hv = hbuf[t * Dn + e];
    p0 += hv * Ww[e * NIn + 0];
    p1 += hv * Ww[e * NIn + 1];
  }
  sp0[tid] = p0;
  sp1[tid] = p1;
  __syncthreads();
  for (int srd = 64; srd; srd >>= 1) {
    if (tid < srd) {
      sp0[tid] += sp0[tid + srd];
      sp1[tid] += sp1[tid + srd];
    }
    __syncthreads();
  }
  const float ww0 = sp0[0], ww1 = sp1[0];

  {
    const int p = tid;
    const float* kp = &kidx[p * CIn];
    float s0 = 0.f, s1 = 0.f;
#pragma unroll 16
    for (int ci = 0; ci < CIn; ++ci) {
      float kc = kp[ci];
      s0 += sqi[ci] * kc;
      s1 += sqi[CIn + ci] * kc;
    }
    float Iv = fmaxf(s0, 0.f) * ww0 + fmaxf(s1, 0.f) * ww1;
    int e = endbuf[p];
    if (!(e <= t && e >= 0)) Iv = NEGV;
    sI[p] = Iv;
  }
  __syncthreads();

  if (tid < 64) {
    float v0 = sI[tid], v1 = sI[tid + 64];
    for (int it = 0; it < TK; ++it) {
      float bv;
      int bi;
      if (v0 >= v1) { bv = v0; bi = tid; } else { bv = v1; bi = tid + 64; }
#pragma unroll
      for (int off = 32; off; off >>= 1) {
        float ov = __shfl_xor(bv, off, 64);
        int oi = __shfl_xor(bi, off, 64);
        if (ov > bv || (ov == bv && oi < bi)) { bv = ov; bi = oi; }
      }
      if (tid == 0) {
        sel[t * TK + it] = bi;
        selok[t * TK + it] = (bv > NEGV * 0.5f) ? 1 : 0;
      }
      if (bi == tid) v0 = -3.4e38f;
      if (bi == tid + 64) v1 = -3.4e38f;
    }
  }
}

// ---------------- attention v2: (t-tile, head) blocks, LDS window K ----------------
// TT=8 tokens per block, one head per block. 256 threads = 4 waves, 2 t per wave.
// Window K rows staged in LDS with XOR swizzle (f4 slot ^ (row&15)).
__global__ __launch_bounds__(256) void attn2_kernel(
    const float* __restrict__ q, const float* __restrict__ ksw,
    const float* __restrict__ kv, const float* __restrict__ kcsa,
    const float* __restrict__ ccsa, const int* __restrict__ sel,
    const int* __restrict__ selok, const float* __restrict__ sink,
    float* __restrict__ attno) {
  constexpr int TT = 8;
  constexpr int RS = TT - 1 + NW;  // 135 staged window rows
  const int t0 = blockIdx.x * TT;
  const int h = blockIdx.y;
  const int tid = threadIdx.x;
  const int wid = tid >> 6, lane = tid & 63;
  const int g = lane >> 4;   // quarter-wave group 0..3
  const int gl = lane & 15;  // lane within group

  __shared__ float4 ks[RS + 1][16];   // swizzled window K slice
  __shared__ float sq[TT][Cn];        // roped q rows
  __shared__ float slog[4][162];      // per-wave logits -> probs
  __shared__ int s_sel[TT][TK];
  __shared__ int s_ok[TT][TK];

  // stage window K rows [t0-127, t0+TT-1], head slice h, swizzled
  for (int idx = tid; idx < RS * 16; idx += 256) {
    int r = idx >> 4, col = idx & 15;
    int src = t0 - (NW - 1) + r;
    float4 v = make_float4(0.f, 0.f, 0.f, 0.f);
    if (src >= 0)
      v = *reinterpret_cast<const float4*>(&ksw[src * Dn + h * Cn + col * 4]);
    ks[r][col ^ (r & 15)] = v;
  }
  // stage q rows
  for (int idx = tid; idx < TT * 16; idx += 256) {
    int r = idx >> 4, col = idx & 15;
    *reinterpret_cast<float4*>(&sq[r][col * 4]) =
        *reinterpret_cast<const float4*>(&q[(t0 + r) * Dn + h * Cn + col * 4]);
  }
  // stage sel / ok
  for (int idx = tid; idx < TT * TK; idx += 256) {
    s_sel[idx >> 5][idx & 31] = sel[(t0 + (idx >> 5)) * TK + (idx & 31)];
    s_ok[idx >> 5][idx & 31] = selok[(t0 + (idx >> 5)) * TK + (idx & 31)];
  }
  __syncthreads();

  float* myslog = slog[wid];

  for (int ii = 0; ii < 2; ++ii) {
    const int dt = wid * 2 + ii;
    const int t = t0 + dt;

    // q row into registers (compile-time indexed only)
    float4 qreg[16];
#pragma unroll
    for (int c4 = 0; c4 < 16; ++c4)
      qreg[c4] = *reinterpret_cast<const float4*>(&sq[dt][c4 * 4]);

    // ---- window logits: lane handles w = lane, lane+64
#pragma unroll
    for (int half = 0; half < 2; ++half) {
      int w = lane + half * 64;
      int r = dt + w;
      int src = t + w - (NW - 1);
      float acc = 0.f;
#pragma unroll
      for (int c4 = 0; c4 < 16; ++c4) {
        float4 kk = ks[r][c4 ^ (r & 15)];
        acc += qreg[c4].x * kk.x + qreg[c4].y * kk.y + qreg[c4].z * kk.z +
               qreg[c4].w * kk.w;
      }
      myslog[TK + w] = (src >= 0) ? acc * 0.125f : NEGV;
    }

    // ---- csa logits: 8 passes x 4 sels (quarter-wave groups)
#pragma unroll 2
    for (int pass = 0; pass < 8; ++pass) {
      int s = pass * 4 + g;
      int se = s_sel[dt][s];
      float4 kk =
          *reinterpret_cast<const float4*>(&kcsa[se * Dn + h * Cn + gl * 4]);
      float4 qq = *reinterpret_cast<const float4*>(&sq[dt][gl * 4]);
      float acc = qq.x * kk.x + qq.y * kk.y + qq.z * kk.z + qq.w * kk.w;
#pragma unroll
      for (int off = 1; off < 16; off <<= 1) acc += __shfl_xor(acc, off, 64);
      if (gl == 0) myslog[s] = s_ok[dt][s] ? acc * 0.125f : NEGV;
    }
    if (lane == 0) myslog[160] = sink[h];

    // ---- softmax over 161 slots
    float x0 = myslog[lane];
    float x1 = myslog[lane + 64];
    float x2 = (lane < 33) ? myslog[lane + 128] : NEGV;
    float m = fmaxf(x0, fmaxf(x1, x2));
#pragma unroll
    for (int off = 32; off; off >>= 1) m = fmaxf(m, __shfl_xor(m, off, 64));
    float e0 = expf(x0 - m), e1 = expf(x1 - m);
    float e2 = (lane < 33) ? expf(x2 - m) : 0.f;
    float sden = e0 + e1 + e2;
#pragma unroll
    for (int off = 32; off; off >>= 1) sden += __shfl_xor(sden, off, 64);
    const float inv = 1.f / sden;
    myslog[lane] = e0 * inv;
    myslog[lane + 64] = e1 * inv;
    if (lane < 33) myslog[lane + 128] = e2 * inv;

    // ---- PV: quarter-wave groups, 4 rows/pass, f4 channels
    float4 acc = make_float4(0.f, 0.f, 0.f, 0.f);
#pragma unroll 4
    for (int pass = 0; pass < 32; ++pass) {
      int w = pass * 4 + g;
      int src = t + w - (NW - 1);
      float pv = myslog[TK + w];
      if (src >= 0) {
        float4 vv =
            *reinterpret_cast<const float4*>(&kv[src * Dn + h * Cn + gl * 4]);
        acc.x += pv * vv.x;
        acc.y += pv * vv.y;
        acc.z += pv * vv.z;
        acc.w += pv * vv.w;
      }
    }
#pragma unroll 2
    for (int pass = 0; pass < 8; ++pass) {
      int s = pass * 4 + g;
      float pv = myslog[s];
      int se = s_sel[dt][s];
      float4 vv =
          *reinterpret_cast<const float4*>(&ccsa[se * Dn + h * Cn + gl * 4]);
      acc.x += pv * vv.x;
      acc.y += pv * vv.y;
      acc.z += pv * vv.z;
      acc.w += pv * vv.w;
    }
    // reduce the 4 groups
    acc.x += __shfl_xor(acc.x, 16, 64);
    acc.y += __shfl_xor(acc.y, 16, 64);
    acc.z += __shfl_xor(acc.z, 16, 64);
    acc.w += __shfl_xor(acc.w, 16, 64);
    acc.x += __shfl_xor(acc.x, 32, 64);
    acc.y += __shfl_xor(acc.y, 32, 64);
    acc.z += __shfl_xor(acc.z, 32, 64);
    acc.w += __shfl_xor(acc.w, 32, 64);
    if (lane < 16)
      *reinterpret_cast<float4*>(&attno[t * Dn + h * Cn + lane * 4]) = acc;
  }
}

// ---------------- host launcher ----------------
extern "C" void kernel_launch(void* const* d_in, const int* in_sizes, int n_in,
                              void* d_out, int out_size, void* d_ws,
                              size_t ws_size, hipStream_t stream) {
  const float* h = (const float*)d_in[0];
  const int* mask = (const int*)d_in[1];
  const int* tok = (const int*)d_in[2];
  const int* endp = (const int*)d_in[3];
  const float* W_dq = (const float*)d_in[5];
  const float* W_uq = (const float*)d_in[6];
  const float* W_csa_kv = (const float*)d_in[7];
  const float* W_csa_z = (const float*)d_in[8];
  const float* B_csa = (const float*)d_in[9];
  const float* W_idx_kv = (const float*)d_in[10];
  const float* W_idx_z = (const float*)d_in[11];
  const float* B_idx = (const float*)d_in[12];
  const float* W_iuq = (const float*)d_in[13];
  const float* W_w = (const float*)d_in[14];
  const float* W_swkv = (const float*)d_in[15];
  const float* qnw = (const float*)d_in[16];
  const float* knw = (const float*)d_in[17];
  const float* W_o = (const float*)d_in[18];
  const float* sink = (const float*)d_in[19];

  float* ws = (float*)d_ws;
  float* q_lat = ws + 0;        // 1024*256
  float* hckv = ws + 262144;    // 1024*512
  float* hcz = ws + 786432;     // 1024*512 (reused as attn-out)
  float* hikv = ws + 1310720;   // 1024*64
  float* hiz = ws + 1376256;    // 1024*64
  float* kvb = ws + 1441792;    // 1024*512
  float* qbuf = ws + 1966080;   // 1024*512 (qraw -> q in place)
  float* qib = ws + 2490368;    // 1024*128
  float* kswb = ws + 2621440;   // 1024*512
  float* ccsa = ws + 3145728;   // 128*512
  float* kcsa = ws + 3211264;   // 128*512
  float* kidx = ws + 3276800;   // 128*64
  int* seli = (int*)(ws + 3284992);   // 1024*32
  int* selok = (int*)(ws + 3317760);  // 1024*32
  float* attno = hcz;                 // alias: hcz dead after phrase_kernel
  float* outp = (float*)d_out;

  // K1: h @ {W_dq, W_csa_kv, W_csa_z, W_idx_kv, W_idx_z, W_swkv}
  {
    SegParams sp;
    const float* b[6] = {W_dq, W_csa_kv, W_csa_z, W_idx_kv, W_idx_z, W_swkv};
    float* c[6] = {q_lat, hckv, hcz, hikv, hiz, kvb};
    int w[6] = {256, 512, 512, 64, 64, 512};
    int ts = 0;
    sp.nseg = 6;
    for (int i = 0; i < 6; ++i) {
      sp.B[i] = b[i]; sp.C[i] = c[i]; sp.width[i] = w[i]; sp.tstart[i] = ts;
      ts += w[i] / 64;
    }
    sgemm_seg<<<dim3(30, 16), 256, 0, stream>>>(h, 512, sp);
  }
  // K2: q_lat @ {W_uq, W_iuq}
  {
    SegParams sp;
    sp.nseg = 2;
    sp.B[0] = W_uq;  sp.C[0] = qbuf; sp.width[0] = 512; sp.tstart[0] = 0;
    sp.B[1] = W_iuq; sp.C[1] = qib;  sp.width[1] = 128; sp.tstart[1] = 8;
    sgemm_seg<<<dim3(10, 16), 256, 0, stream>>>(q_lat, 256, sp);
  }
  // K3: phrase aggregation
  phrase_kernel<<<Pn, 512, 0, stream>>>(mask, tok, endp, hckv, hcz, hikv, hiz,
                                        B_csa, B_idx, knw, ccsa, kcsa, kidx);
  // K5: q (in place) and k_sw
  rmsrope_kernel<<<Tn, 512, 0, stream>>>(qbuf, kvb, kswb, qnw, knw);
  // K4: scores + top-32
  score_topk_kernel<<<Tn, 128, 0, stream>>>(h, W_w, qib, kidx, endp, seli,
                                            selok);
  // K6: attention v2 (writes attno, aliases hcz)
  attn2_kernel<<<dim3(Tn / 8, Hn), 256, 0, stream>>>(qbuf, kswb, kvb, kcsa,
                                                     ccsa, seli, selok, sink,
                                                     attno);
  // K7: attno @ W_o -> out
  {
    SegParams sp;
    sp.nseg = 1;
    sp.B[0] = W_o; sp.C[0] = outp; sp.width[0] = 512; sp.tstart[0] = 0;
    sgemm_seg<<<dim3(8, 16), 256, 0, stream>>>(attno, 512, sp);
  }
  (void)in_sizes; (void)n_in; (void)out_size; (void)ws_size;
}

// Round 3
// 159.830 us; speedup vs baseline: 1.3482x; 1.1373x over previous
//
#include <hip/hip_runtime.h>
#include <cmath>

// ---------------- constants (match reference) ----------------
static constexpr int Tn = 1024, Dn = 512, Hn = 8, Cn = 64, DQn = 256,
                     NIn = 2, CIn = 64, TK = 32, LM = 16, NW = 128, Pn = 128;
#define NEGV (-1e30f)

// ---------------- segmented fp32 GEMM ----------------
struct SegParams {
  const float* B[6];
  float* C[6];
  int width[6];   // each a multiple of 64
  int tstart[6];  // starting col-tile index of segment
  int nseg;
};

__global__ __launch_bounds__(256) void sgemm_seg(const float* __restrict__ A,
                                                 int K, SegParams sp) {
  const int ct = blockIdx.x, rt = blockIdx.y;
  int s = 0;
  while (s + 1 < sp.nseg && ct >= sp.tstart[s + 1]) ++s;
  const float* __restrict__ Bm = sp.B[s];
  float* __restrict__ Cm = sp.C[s];
  const int ldb = sp.width[s];
  const int col0 = (ct - sp.tstart[s]) * 64;
  const int row0 = rt * 64;

  __shared__ float As[16][64];
  __shared__ float Bs[16][64];

  const int tid = threadIdx.x;
  const int tx = tid & 15, ty = tid >> 4;
  const int am = tid & 63, ak4 = (tid >> 6) << 2;
  const int bn4 = (tid & 15) << 2, bk = tid >> 4;

  float acc[4][4] = {};

  for (int k0 = 0; k0 < K; k0 += 16) {
    float4 av = *reinterpret_cast<const float4*>(&A[(row0 + am) * K + k0 + ak4]);
    As[ak4 + 0][am] = av.x;
    As[ak4 + 1][am] = av.y;
    As[ak4 + 2][am] = av.z;
    As[ak4 + 3][am] = av.w;
    *reinterpret_cast<float4*>(&Bs[bk][bn4]) =
        *reinterpret_cast<const float4*>(&Bm[(k0 + bk) * ldb + col0 + bn4]);
    __syncthreads();
#pragma unroll
    for (int k = 0; k < 16; ++k) {
      float4 a4 = *reinterpret_cast<const float4*>(&As[k][ty << 2]);
      float4 b4 = *reinterpret_cast<const float4*>(&Bs[k][tx << 2]);
      float a[4] = {a4.x, a4.y, a4.z, a4.w};
      float b[4] = {b4.x, b4.y, b4.z, b4.w};
#pragma unroll
      for (int i = 0; i < 4; ++i)
#pragma unroll
        for (int j = 0; j < 4; ++j) acc[i][j] += a[i] * b[j];
    }
    __syncthreads();
  }
#pragma unroll
  for (int i = 0; i < 4; ++i) {
    float4 v = make_float4(acc[i][0], acc[i][1], acc[i][2], acc[i][3]);
    *reinterpret_cast<float4*>(&Cm[(row0 + (ty << 2) + i) * ldb + col0 + (tx << 2)]) = v;
  }
}

// ---------------- phrase aggregation ----------------
__global__ __launch_bounds__(512) void phrase_kernel(
    const int* __restrict__ maskbuf, const int* __restrict__ tokbuf,
    const int* __restrict__ endbuf, const float* __restrict__ hckv,
    const float* __restrict__ hcz, const float* __restrict__ hikv,
    const float* __restrict__ hiz, const float* __restrict__ Bcsa,
    const float* __restrict__ Bidx, const float* __restrict__ knw,
    float* __restrict__ ccsa, float* __restrict__ kcsa,
    float* __restrict__ kidx) {
  const int p = blockIdx.x;
  const int tid = threadIdx.x;
  __shared__ int s_bytemode;
  __shared__ int s_tok[LM];
  __shared__ int s_m[LM];
  __shared__ int s_pos, s_anyv;

  if (tid == 0) s_bytemode = 0;
  __syncthreads();
  {
    unsigned w = ((const unsigned*)maskbuf)[tid];  // tid in [0,512)
    if (w > 1u) atomicOr(&s_bytemode, 1);
  }
  __syncthreads();
  const int bytemode = s_bytemode;
  if (tid < LM) {
    int mv;
    if (bytemode)
      mv = ((const unsigned char*)maskbuf)[p * LM + tid] != 0;
    else
      mv = maskbuf[p * LM + tid] != 0;
    s_m[tid] = mv;
    s_tok[tid] = tokbuf[p * LM + tid];
  }
  if (tid == 0) {
    int e = endbuf[p];
    s_pos = min(max(e, 0), Tn - 1);
  }
  __syncthreads();
  if (tid == 0) {
    int any = 0;
    for (int l = 0; l < LM; ++l) any |= s_m[l];
    s_anyv = any;
  }
  __syncthreads();
  const int anyv = s_anyv;
  const int pos = s_pos;
  const int c = tid & 63;
  const float fr = (float)pos * powf(10000.0f, -(float)(c & 31) / 32.0f);
  const float cv = cosf(fr), sv = sinf(fr);
  const float sgn = (c < 32) ? -1.f : 1.f;

  {
    float z[LM];
    float zmax = NEGV;
#pragma unroll
    for (int l = 0; l < LM; ++l) {
      float zv = hcz[s_tok[l] * Dn + tid] + Bcsa[l * (Hn * Cn) + tid];
      zv = s_m[l] ? zv : NEGV;
      z[l] = zv;
      zmax = fmaxf(zmax, zv);
    }
    float den = 0.f, num = 0.f;
#pragma unroll
    for (int l = 0; l < LM; ++l) {
      float e = expf(z[l] - zmax);
      den += e;
      num += e * hckv[s_tok[l] * Dn + tid];
    }
    float cc = anyv ? (num / den) : 0.f;
    ccsa[p * (Hn * Cn) + tid] = cc;

    float ss = cc * cc;
#pragma unroll
    for (int off = 32; off; off >>= 1) ss += __shfl_xor(ss, off, 64);
    float kn = cc * rsqrtf(ss / (float)Cn + 1e-6f) * knw[c];
    float pr = __shfl_xor(kn, 32, 64);
    kcsa[p * (Hn * Cn) + tid] = kn * cv + sgn * pr * sv;
  }

  if (tid < CIn) {
    float zk[LM];
    float zm = NEGV;
#pragma unroll
    for (int l = 0; l < LM; ++l) {
      float zv = hiz[s_tok[l] * CIn + tid] + Bidx[l * CIn + tid];
      zv = s_m[l] ? zv : NEGV;
      zk[l] = zv;
      zm = fmaxf(zm, zv);
    }
    float dk = 0.f, nk = 0.f;
#pragma unroll
    for (int l = 0; l < LM; ++l) {
      float e = expf(zk[l] - zm);
      dk += e;
      nk += e * hikv[s_tok[l] * CIn + tid];
    }
    float ki = anyv ? (nk / dk) : 0.f;
    float pr = __shfl_xor(ki, 32, 64);
    kidx[p * CIn + tid] = ki * cv + sgn * pr * sv;
  }
}

// ---------------- RMS+RoPE for q (in place) and k_sw ----------------
__global__ __launch_bounds__(512) void rmsrope_kernel(
    float* __restrict__ q, const float* __restrict__ kv,
    float* __restrict__ ksw, const float* __restrict__ qnw,
    const float* __restrict__ knw) {
  const int t = blockIdx.x;
  const int tid = threadIdx.x;
  const int c = tid & 63;
  const float fr = (float)t * powf(10000.0f, -(float)(c & 31) / 32.0f);
  const float cv = cosf(fr), sv = sinf(fr);
  const float sgn = (c < 32) ? -1.f : 1.f;
  {
    float x = q[t * Dn + tid];
    float ss = x * x;
#pragma unroll
    for (int off = 32; off; off >>= 1) ss += __shfl_xor(ss, off, 64);
    float xr = x * rsqrtf(ss / (float)Cn + 1e-6f) * qnw[c];
    float pr = __shfl_xor(xr, 32, 64);
    q[t * Dn + tid] = xr * cv + sgn * pr * sv;
  }
  {
    float y = kv[t * Dn + tid];
    float ss = y * y;
#pragma unroll
    for (int off = 32; off; off >>= 1) ss += __shfl_xor(ss, off, 64);
    float yr = y * rsqrtf(ss / (float)Cn + 1e-6f) * knw[c];
    float pr = __shfl_xor(yr, 32, 64);
    ksw[t * Dn + tid] = yr * cv + sgn * pr * sv;
  }
}

// ---------------- phrase scores + top-32 ----------------
__global__ __launch_bounds__(128) void score_topk_kernel(
    const float* __restrict__ hbuf, const float* __restrict__ Ww,
    const float* __restrict__ qi, const float* __restrict__ kidx,
    const int* __restrict__ endbuf, int* __restrict__ sel,
    int* __restrict__ selok) {
  const int t = blockIdx.x;
  const int tid = threadIdx.x;
  __shared__ float sqi[NIn * CIn];
  __shared__ float sI[Pn];
  __shared__ float sp0[128], sp1[128];

  sqi[tid] = qi[t * (NIn * CIn) + tid];
  float p0 = 0.f, p1 = 0.f;
#pragma unroll
  for (int e4 = 0; e4 < 4; ++e4) {
    int e = tid * 4 + e4;
    float hv = hbuf[t * Dn + e];
    p0 += hv * Ww[e * NIn + 0];
    p1 += hv * Ww[e * NIn + 1];
  }
  sp0[tid] = p0;
  sp1[tid] = p1;
  __syncthreads();
  for (int srd = 64; srd; srd >>= 1) {
    if (tid < srd) {
      sp0[tid] += sp0[tid + srd];
      sp1[tid] += sp1[tid + srd];
    }
    __syncthreads();
  }
  const float ww0 = sp0[0], ww1 = sp1[0];

  {
    const int p = tid;
    const float* kp = &kidx[p * CIn];
    float s0 = 0.f, s1 = 0.f;
#pragma unroll 16
    for (int ci = 0; ci < CIn; ++ci) {
      float kc = kp[ci];
      s0 += sqi[ci] * kc;
      s1 += sqi[CIn + ci] * kc;
    }
    float Iv = fmaxf(s0, 0.f) * ww0 + fmaxf(s1, 0.f) * ww1;
    int e = endbuf[p];
    if (!(e <= t && e >= 0)) Iv = NEGV;
    sI[p] = Iv;
  }
  __syncthreads();

  if (tid < 64) {
    float v0 = sI[tid], v1 = sI[tid + 64];
    for (int it = 0; it < TK; ++it) {
      float bv;
      int bi;
      if (v0 >= v1) { bv = v0; bi = tid; } else { bv = v1; bi = tid + 64; }
#pragma unroll
      for (int off = 32; off; off >>= 1) {
        float ov = __shfl_xor(bv, off, 64);
        int oi = __shfl_xor(bi, off, 64);
        if (ov > bv || (ov == bv && oi < bi)) { bv = ov; bi = oi; }
      }
      if (tid == 0) {
        sel[t * TK + it] = bi;
        selok[t * TK + it] = (bv > NEGV * 0.5f) ? 1 : 0;
      }
      if (bi == tid) v0 = -3.4e38f;
      if (bi == tid + 64) v1 = -3.4e38f;
    }
  }
}

// ---------------- attention v3: one wave per (t,h), no K staging ----------------
// Quarter-wave float4 groups: 16 lanes cover the 64-channel head slice (one
// contiguous 256B segment, fully coalesced); 4 groups process 4 rows/pass.
// All reads come straight from L2 (window K/V rows are L2-resident).
__global__ __launch_bounds__(256) void attn3_kernel(
    const float* __restrict__ q, const float* __restrict__ ksw,
    const float* __restrict__ kv, const float* __restrict__ kcsa,
    const float* __restrict__ ccsa, const int* __restrict__ sel,
    const int* __restrict__ selok, const float* __restrict__ sink,
    float* __restrict__ attno) {
  const int tid = threadIdx.x;
  const int wid = tid >> 6, lane = tid & 63;
  const int g = lane >> 4;   // group 0..3 (row within pass)
  const int gl = lane & 15;  // lane within group (channel/4)
  const int pair = blockIdx.x * 4 + wid;
  const int t = pair >> 3, h = pair & 7;

  __shared__ float slog[4][164];
  __shared__ int s_sel[4][TK];
  __shared__ int s_ok[4][TK];

  if (lane < TK) {
    s_sel[wid][lane] = sel[t * TK + lane];
    s_ok[wid][lane] = selok[t * TK + lane];
  }
  const int hc = h * Cn + gl * 4;
  const float4 qf = *reinterpret_cast<const float4*>(&q[t * Dn + hc]);
  float* myslog = slog[wid];

  // ---- window logits: 32 passes, rows w = pass*4+g
#pragma unroll 4
  for (int pass = 0; pass < 32; ++pass) {
    int w = pass * 4 + g;
    int src = t + w - (NW - 1);
    int srcc = max(src, 0);
    float4 kk = *reinterpret_cast<const float4*>(&ksw[srcc * Dn + hc]);
    float acc = qf.x * kk.x + qf.y * kk.y + qf.z * kk.z + qf.w * kk.w;
#pragma unroll
    for (int off = 1; off < 16; off <<= 1) acc += __shfl_xor(acc, off, 64);
    if (gl == 0) myslog[TK + w] = (src >= 0) ? acc * 0.125f : NEGV;
  }
  // ---- csa logits: 8 passes, rows s = pass*4+g
#pragma unroll 2
  for (int pass = 0; pass < 8; ++pass) {
    int s = pass * 4 + g;
    int se = s_sel[wid][s];
    float4 kk = *reinterpret_cast<const float4*>(&kcsa[se * Dn + hc]);
    float acc = qf.x * kk.x + qf.y * kk.y + qf.z * kk.z + qf.w * kk.w;
#pragma unroll
    for (int off = 1; off < 16; off <<= 1) acc += __shfl_xor(acc, off, 64);
    if (gl == 0) myslog[s] = s_ok[wid][s] ? acc * 0.125f : NEGV;
  }
  if (lane == 0) myslog[160] = sink[h];

  // ---- softmax over 161 slots (wave-parallel)
  float x0 = myslog[lane];
  float x1 = myslog[lane + 64];
  float x2 = (lane < 33) ? myslog[lane + 128] : NEGV;
  float m = fmaxf(x0, fmaxf(x1, x2));
#pragma unroll
  for (int off = 32; off; off >>= 1) m = fmaxf(m, __shfl_xor(m, off, 64));
  float e0 = expf(x0 - m), e1 = expf(x1 - m);
  float e2 = (lane < 33) ? expf(x2 - m) : 0.f;
  float sden = e0 + e1 + e2;
#pragma unroll
  for (int off = 32; off; off >>= 1) sden += __shfl_xor(sden, off, 64);
  const float inv = 1.f / sden;
  myslog[lane] = e0 * inv;
  myslog[lane + 64] = e1 * inv;
  if (lane < 33) myslog[lane + 128] = e2 * inv;

  // ---- PV: window 32 passes + csa 8 passes
  float4 acc = make_float4(0.f, 0.f, 0.f, 0.f);
#pragma unroll 4
  for (int pass = 0; pass < 32; ++pass) {
    int w = pass * 4 + g;
    int src = t + w - (NW - 1);
    int srcc = max(src, 0);
    float pv = myslog[TK + w];
    pv = (src >= 0) ? pv : 0.f;
    float4 vv = *reinterpret_cast<const float4*>(&kv[srcc * Dn + hc]);
    acc.x += pv * vv.x;
    acc.y += pv * vv.y;
    acc.z += pv * vv.z;
    acc.w += pv * vv.w;
  }
#pragma unroll 2
  for (int pass = 0; pass < 8; ++pass) {
    int s = pass * 4 + g;
    float pv = myslog[s];
    int se = s_sel[wid][s];
    float4 vv = *reinterpret_cast<const float4*>(&ccsa[se * Dn + hc]);
    acc.x += pv * vv.x;
    acc.y += pv * vv.y;
    acc.z += pv * vv.z;
    acc.w += pv * vv.w;
  }
  // reduce the 4 groups (each lane<16 ends with the full channel sum)
  acc.x += __shfl_xor(acc.x, 16, 64);
  acc.y += __shfl_xor(acc.y, 16, 64);
  acc.z += __shfl_xor(acc.z, 16, 64);
  acc.w += __shfl_xor(acc.w, 16, 64);
  acc.x += __shfl_xor(acc.x, 32, 64);
  acc.y += __shfl_xor(acc.y, 32, 64);
  acc.z += __shfl_xor(acc.z, 32, 64);
  acc.w += __shfl_xor(acc.w, 32, 64);
  if (lane < 16)
    *reinterpret_cast<float4*>(&attno[t * Dn + h * Cn + lane * 4]) = acc;
}

// ---------------- host launcher ----------------
extern "C" void kernel_launch(void* const* d_in, const int* in_sizes, int n_in,
                              void* d_out, int out_size, void* d_ws,
                              size_t ws_size, hipStream_t stream) {
  const float* h = (const float*)d_in[0];
  const int* mask = (const int*)d_in[1];
  const int* tok = (const int*)d_in[2];
  const int* endp = (const int*)d_in[3];
  const float* W_dq = (const float*)d_in[5];
  const float* W_uq = (const float*)d_in[6];
  const float* W_csa_kv = (const float*)d_in[7];
  const float* W_csa_z = (const float*)d_in[8];
  const float* B_csa = (const float*)d_in[9];
  const float* W_idx_kv = (const float*)d_in[10];
  const float* W_idx_z = (const float*)d_in[11];
  const float* B_idx = (const float*)d_in[12];
  const float* W_iuq = (const float*)d_in[13];
  const float* W_w = (const float*)d_in[14];
  const float* W_swkv = (const float*)d_in[15];
  const float* qnw = (const float*)d_in[16];
  const float* knw = (const float*)d_in[17];
  const float* W_o = (const float*)d_in[18];
  const float* sink = (const float*)d_in[19];

  float* ws = (float*)d_ws;
  float* q_lat = ws + 0;        // 1024*256
  float* hckv = ws + 262144;    // 1024*512
  float* hcz = ws + 786432;     // 1024*512 (reused as attn-out)
  float* hikv = ws + 1310720;   // 1024*64
  float* hiz = ws + 1376256;    // 1024*64
  float* kvb = ws + 1441792;    // 1024*512
  float* qbuf = ws + 1966080;   // 1024*512 (qraw -> q in place)
  float* qib = ws + 2490368;    // 1024*128
  float* kswb = ws + 2621440;   // 1024*512
  float* ccsa = ws + 3145728;   // 128*512
  float* kcsa = ws + 3211264;   // 128*512
  float* kidx = ws + 3276800;   // 128*64
  int* seli = (int*)(ws + 3284992);   // 1024*32
  int* selok = (int*)(ws + 3317760);  // 1024*32
  float* attno = hcz;                 // alias: hcz dead after phrase_kernel
  float* outp = (float*)d_out;

  // K1: h @ {W_dq, W_csa_kv, W_csa_z, W_idx_kv, W_idx_z, W_swkv}
  {
    SegParams sp;
    const float* b[6] = {W_dq, W_csa_kv, W_csa_z, W_idx_kv, W_idx_z, W_swkv};
    float* c[6] = {q_lat, hckv, hcz, hikv, hiz, kvb};
    int w[6] = {256, 512, 512, 64, 64, 512};
    int ts = 0;
    sp.nseg = 6;
    for (int i = 0; i < 6; ++i) {
      sp.B[i] = b[i]; sp.C[i] = c[i]; sp.width[i] = w[i]; sp.tstart[i] = ts;
      ts += w[i] / 64;
    }
    sgemm_seg<<<dim3(30, 16), 256, 0, stream>>>(h, 512, sp);
  }
  // K2: q_lat @ {W_uq, W_iuq}
  {
    SegParams sp;
    sp.nseg = 2;
    sp.B[0] = W_uq;  sp.C[0] = qbuf; sp.width[0] = 512; sp.tstart[0] = 0;
    sp.B[1] = W_iuq; sp.C[1] = qib;  sp.width[1] = 128; sp.tstart[1] = 8;
    sgemm_seg<<<dim3(10, 16), 256, 0, stream>>>(q_lat, 256, sp);
  }
  // K3: phrase aggregation
  phrase_kernel<<<Pn, 512, 0, stream>>>(mask, tok, endp, hckv, hcz, hikv, hiz,
                                        B_csa, B_idx, knw, ccsa, kcsa, kidx);
  // K5: q (in place) and k_sw
  rmsrope_kernel<<<Tn, 512, 0, stream>>>(qbuf, kvb, kswb, qnw, knw);
  // K4: scores + top-32
  score_topk_kernel<<<Tn, 128, 0, stream>>>(h, W_w, qib, kidx, endp, seli,
                                            selok);
  // K6: attention v3 (writes attno, aliases hcz)
  attn3_kernel<<<dim3(Tn * Hn / 4), 256, 0, stream>>>(qbuf, kswb, kvb, kcsa,
                                                      ccsa, seli, selok, sink,
                                                      attno);
  // K7: attno @ W_o -> out
  {
    SegParams sp;
    sp.nseg = 1;
    sp.B[0] = W_o; sp.C[0] = outp; sp.width[0] = 512; sp.tstart[0] = 0;
    sgemm_seg<<<dim3(8, 16), 256, 0, stream>>>(attno, 512, sp);
  }
  (void)in_sizes; (void)n_in; (void)out_size; (void)ws_size;
}